// Round 1
// baseline (594.325 us; speedup 1.0000x reference)
//
#include <hip/hip_runtime.h>
#include <hip/hip_fp16.h>

// Qwen3 attention block: B=2 S=2048 HID=1024 NH=16 NKV=8 HD=128, causal.
// Full f16-MFMA pipeline; fp32 accumulate everywhere.

typedef _Float16 f16;
typedef __attribute__((ext_vector_type(8))) _Float16 f16x8;
typedef __attribute__((ext_vector_type(4))) _Float16 f16x4;
typedef __attribute__((ext_vector_type(4))) float f32x4;

#define B_ 2
#define S_ 2048
#define HID_ 1024
#define NH_ 16
#define NKV_ 8
#define HD_ 128

__constant__ const float kEps = 1e-6f;
__constant__ const float kScale = 0.08838834764831845f;  // 1/sqrt(128), folded into Q

// ---------------------------------------------------------------- cast f32->f16
__global__ __launch_bounds__(256) void cast_f32_f16(const float* __restrict__ in,
                                                    f16* __restrict__ out, int n) {
  int i = (blockIdx.x * 256 + threadIdx.x) * 4;
  if (i >= n) return;
  f32x4 v = *reinterpret_cast<const f32x4*>(in + i);
  f16x4 o;
  o.x = (f16)v.x; o.y = (f16)v.y; o.z = (f16)v.z; o.w = (f16)v.w;
  *reinterpret_cast<f16x4*>(out + i) = o;
}

// ------------------------------------------------- C[M,N] = A[M,K] * B[N,K]^T
// 128x128 tile, BK=32, 4 waves each owning 64x64 (4x4 of 16x16x32 MFMA).
__global__ __launch_bounds__(256) void gemm_bt(const f16* __restrict__ A,
                                               const f16* __restrict__ Bm,
                                               float* __restrict__ C,
                                               int M, int N, int K) {
  __shared__ f16 As[128][32];
  __shared__ f16 Bs[128][32];
  const int tid = threadIdx.x;
  const int lane = tid & 63;
  const int wave = tid >> 6;
  const int cl = lane & 15;
  const int quad = lane >> 4;
  const int wm = (wave >> 1) * 64;
  const int wn = (wave & 1) * 64;
  const int tm = blockIdx.y * 128;
  const int tn = blockIdx.x * 128;
  const int r0 = tid >> 2;          // staging row 0..63
  const int c0 = (tid & 3) * 8;     // staging col offset (elements)

  const f16* Ab = A + (size_t)(tm + r0) * K + c0;
  const f16* Bb = Bm + (size_t)(tn + r0) * K + c0;

  f32x4 acc[4][4] = {};

  for (int k0 = 0; k0 < K; k0 += 32) {
    *reinterpret_cast<int4*>(&As[r0][c0]) = *reinterpret_cast<const int4*>(Ab + k0);
    *reinterpret_cast<int4*>(&As[r0 + 64][c0]) =
        *reinterpret_cast<const int4*>(Ab + (size_t)64 * K + k0);
    *reinterpret_cast<int4*>(&Bs[r0][c0]) = *reinterpret_cast<const int4*>(Bb + k0);
    *reinterpret_cast<int4*>(&Bs[r0 + 64][c0]) =
        *reinterpret_cast<const int4*>(Bb + (size_t)64 * K + k0);
    __syncthreads();
    f16x8 af[4], bf[4];
#pragma unroll
    for (int mi = 0; mi < 4; ++mi)
      af[mi] = *reinterpret_cast<const f16x8*>(&As[wm + mi * 16 + cl][quad * 8]);
#pragma unroll
    for (int ni = 0; ni < 4; ++ni)
      bf[ni] = *reinterpret_cast<const f16x8*>(&Bs[wn + ni * 16 + cl][quad * 8]);
#pragma unroll
    for (int mi = 0; mi < 4; ++mi)
#pragma unroll
      for (int ni = 0; ni < 4; ++ni)
        acc[mi][ni] =
            __builtin_amdgcn_mfma_f32_16x16x32_f16(af[mi], bf[ni], acc[mi][ni], 0, 0, 0);
    __syncthreads();
  }
  // C/D layout (verified): col = lane&15, row = quad*4 + reg
#pragma unroll
  for (int mi = 0; mi < 4; ++mi)
#pragma unroll
    for (int ni = 0; ni < 4; ++ni)
#pragma unroll
      for (int r = 0; r < 4; ++r)
        C[(size_t)(tm + wm + mi * 16 + quad * 4 + r) * N + tn + wn + ni * 16 + cl] =
            acc[mi][ni][r];
}

// -------------------------- RMSNorm + RoPE + transpose for Q,K (wave per row)
// qf: (B*S, NH*HD) fp32   kf: (B*S, NKV*HD) fp32
// qt: (B*NH, S, HD) f16 (pre-scaled by 1/sqrt(HD))   kt: (B*NKV, S, HD) f16
__global__ __launch_bounds__(256) void rope_norm(
    const float* __restrict__ qf, const float* __restrict__ kf,
    const float* __restrict__ cosT, const float* __restrict__ sinT,
    const float* __restrict__ qw, const float* __restrict__ kw,
    f16* __restrict__ qt, f16* __restrict__ kt) {
  const int gw = blockIdx.x * 4 + (threadIdx.x >> 6);
  const int lane = threadIdx.x & 63;
  const int head = gw % 24;
  const int bs = gw / 24;
  const bool isq = head < 16;
  const float* src = isq ? qf + (size_t)bs * 2048 + head * 128
                         : kf + (size_t)bs * 1024 + (head - 16) * 128;
  const float x1 = src[lane];
  const float x2 = src[lane + 64];
  float ss = x1 * x1 + x2 * x2;
#pragma unroll
  for (int off = 32; off >= 1; off >>= 1) ss += __shfl_xor(ss, off);
  const float rms = rsqrtf(ss * (1.0f / 128.0f) + kEps);
  const float* w = isq ? qw : kw;
  const float n1 = x1 * rms * w[lane];
  const float n2 = x2 * rms * w[lane + 64];
  const float* cb = cosT + (size_t)bs * 128;
  const float* sb = sinT + (size_t)bs * 128;
  // rotate_half: out[d] = x[d]*cos[d] + (d<64 ? -x[d+64] : x[d-64])*sin[d]
  const float o1 = n1 * cb[lane] - n2 * sb[lane];
  const float o2 = n2 * cb[lane + 64] + n1 * sb[lane + 64];
  const int b = bs >> 11;
  const int s = bs & 2047;
  f16* dst;
  float sc;
  if (isq) {
    dst = qt + ((size_t)(b * 16 + head) * 2048 + s) * 128;
    sc = kScale;
  } else {
    dst = kt + ((size_t)(b * 8 + (head - 16)) * 2048 + s) * 128;
    sc = 1.0f;
  }
  dst[lane] = (f16)(o1 * sc);
  dst[lane + 64] = (f16)(o2 * sc);
}

// ------------------------------- V: (B*S, NKV*HD) fp32 -> (B*NKV, HD, S) f16
__global__ __launch_bounds__(256) void v_transpose(const float* __restrict__ vf,
                                                   f16* __restrict__ vt) {
  __shared__ f16 tile[64][136];  // 64 s x 128 d, padded
  const int bh = blockIdx.y;
  const int b = bh >> 3, h = bh & 7;
  const int s0 = blockIdx.x * 64;
  const int tid = threadIdx.x;
#pragma unroll
  for (int i = 0; i < 8; ++i) {
    int c = tid + i * 256;  // 0..2047 float4 chunks
    int s = c >> 5;
    int d0 = (c & 31) * 4;
    f32x4 v = *reinterpret_cast<const f32x4*>(
        vf + (size_t)(b * 2048 + s0 + s) * 1024 + h * 128 + d0);
    tile[s][d0 + 0] = (f16)v.x;
    tile[s][d0 + 1] = (f16)v.y;
    tile[s][d0 + 2] = (f16)v.z;
    tile[s][d0 + 3] = (f16)v.w;
  }
  __syncthreads();
#pragma unroll
  for (int i = 0; i < 4; ++i) {
    int c = tid + i * 256;  // 0..1023 16B chunks
    int d = c >> 3;
    int sB = (c & 7) * 8;
    f16x8 o;
#pragma unroll
    for (int j = 0; j < 8; ++j) o[j] = tile[sB + j][d];
    *reinterpret_cast<f16x8*>(vt + ((size_t)(b * 8 + h) * 128 + d) * 2048 + s0 + sB) = o;
  }
}

// ------------------------------------------------------- flash attention (causal)
// block = (64 q rows, one (b,h)); 4 waves each own 16 q rows; K-tiles of 32.
__global__ __launch_bounds__(256) void attn(const f16* __restrict__ Qt,
                                            const f16* __restrict__ Kt,
                                            const f16* __restrict__ Vt,
                                            f16* __restrict__ Ot) {
  __shared__ f16 Ks[32][128];    // key rows x d
  __shared__ f16 Vs[128][32];    // d x key rows (pre-transposed global)
  __shared__ f16 Ps[4][16][32];  // per-wave P round-trip C-layout -> A-layout
  const int bh = blockIdx.y;
  const int b = bh >> 4, h = bh & 15;
  const int kv = h >> 1;  // n_rep = 2
  const int q0 = blockIdx.x * 64;
  const int tid = threadIdx.x;
  const int lane = tid & 63, wv = tid >> 6;
  const int cl = lane & 15, quad = lane >> 4;

  const f16* qbase = Qt + ((size_t)bh * 2048 + q0 + wv * 16 + cl) * 128;
  f16x8 aq[4];
#pragma unroll
  for (int kk = 0; kk < 4; ++kk)
    aq[kk] = *reinterpret_cast<const f16x8*>(qbase + kk * 32 + quad * 8);

  const f16* kbase = Kt + (size_t)(b * 8 + kv) * 2048 * 128;
  const f16* vbase = Vt + (size_t)(b * 8 + kv) * 128 * 2048;

  float m_r[4], l_r[4];
#pragma unroll
  for (int r = 0; r < 4; ++r) {
    m_r[r] = -1e30f;
    l_r[r] = 0.f;
  }
  f32x4 oacc[8] = {};
  const int qg_base = q0 + wv * 16 + quad * 4;

  for (int kt0 = 0; kt0 < q0 + 64; kt0 += 32) {
#pragma unroll
    for (int i = 0; i < 2; ++i) {
      int c = tid + i * 256;
      int krow = c >> 4, d0 = (c & 15) * 8;
      *reinterpret_cast<int4*>(&Ks[krow][d0]) =
          *reinterpret_cast<const int4*>(kbase + (size_t)(kt0 + krow) * 128 + d0);
      int dr = c >> 2, koff = (c & 3) * 8;
      *reinterpret_cast<int4*>(&Vs[dr][koff]) =
          *reinterpret_cast<const int4*>(vbase + (size_t)dr * 2048 + kt0 + koff);
    }
    __syncthreads();
    f32x4 sacc[2] = {};
#pragma unroll
    for (int kk = 0; kk < 4; ++kk)
#pragma unroll
      for (int ni = 0; ni < 2; ++ni) {
        f16x8 bk = *reinterpret_cast<const f16x8*>(&Ks[ni * 16 + cl][kk * 32 + quad * 8]);
        sacc[ni] = __builtin_amdgcn_mfma_f32_16x16x32_f16(aq[kk], bk, sacc[ni], 0, 0, 0);
      }
    // causal mask: score element (row=quad*4+r, col=kt0+ni*16+cl)
#pragma unroll
    for (int ni = 0; ni < 2; ++ni) {
      const int kg = kt0 + ni * 16 + cl;
#pragma unroll
      for (int r = 0; r < 4; ++r)
        if (kg > qg_base + r) sacc[ni][r] = -1e30f;
    }
    float mx[4], al[4], rs[4];
#pragma unroll
    for (int r = 0; r < 4; ++r) mx[r] = fmaxf(sacc[0][r], sacc[1][r]);
#pragma unroll
    for (int off = 1; off < 16; off <<= 1)
#pragma unroll
      for (int r = 0; r < 4; ++r) mx[r] = fmaxf(mx[r], __shfl_xor(mx[r], off));
#pragma unroll
    for (int r = 0; r < 4; ++r) {
      const float nm = fmaxf(m_r[r], mx[r]);
      al[r] = __expf(m_r[r] - nm);
      m_r[r] = nm;
      const float p0 = __expf(sacc[0][r] - nm);
      const float p1 = __expf(sacc[1][r] - nm);
      sacc[0][r] = p0;
      sacc[1][r] = p1;
      rs[r] = p0 + p1;
    }
#pragma unroll
    for (int off = 1; off < 16; off <<= 1)
#pragma unroll
      for (int r = 0; r < 4; ++r) rs[r] += __shfl_xor(rs[r], off);
#pragma unroll
    for (int r = 0; r < 4; ++r) l_r[r] = l_r[r] * al[r] + rs[r];
#pragma unroll
    for (int ni = 0; ni < 2; ++ni)
#pragma unroll
      for (int r = 0; r < 4; ++r)
        Ps[wv][quad * 4 + r][ni * 16 + cl] = (f16)sacc[ni][r];
#pragma unroll
    for (int dg = 0; dg < 8; ++dg)
#pragma unroll
      for (int r = 0; r < 4; ++r) oacc[dg][r] *= al[r];
    __syncthreads();  // P visible (cross-lane) before A-layout read
    f16x8 ap = *reinterpret_cast<const f16x8*>(&Ps[wv][cl][quad * 8]);
#pragma unroll
    for (int dg = 0; dg < 8; ++dg) {
      f16x8 bv = *reinterpret_cast<const f16x8*>(&Vs[dg * 16 + cl][quad * 8]);
      oacc[dg] = __builtin_amdgcn_mfma_f32_16x16x32_f16(ap, bv, oacc[dg], 0, 0, 0);
    }
    __syncthreads();  // protect Ks/Vs before next stage
  }
#pragma unroll
  for (int r = 0; r < 4; ++r) {
    const int qg = qg_base + r;
    const float inv = 1.0f / l_r[r];
#pragma unroll
    for (int dg = 0; dg < 8; ++dg)
      Ot[(size_t)(b * 2048 + qg) * 2048 + h * 128 + dg * 16 + cl] =
          (f16)(oacc[dg][r] * inv);
  }
}

// ---------------------------------------------------------------------- launch
extern "C" void kernel_launch(void* const* d_in, const int* in_sizes, int n_in,
                              void* d_out, int out_size, void* d_ws, size_t ws_size,
                              hipStream_t stream) {
  (void)in_sizes; (void)n_in; (void)out_size; (void)ws_size;
  const float* hidden = (const float*)d_in[0];
  const float* cosT = (const float*)d_in[1];
  const float* sinT = (const float*)d_in[2];
  // d_in[3] = attention_mask: exactly causal triu * -1e9 -> computed analytically
  const float* Wq = (const float*)d_in[4];
  const float* Wk = (const float*)d_in[5];
  const float* Wv = (const float*)d_in[6];
  const float* Wo = (const float*)d_in[7];
  const float* qnw = (const float*)d_in[8];
  const float* knw = (const float*)d_in[9];
  float* out = (float*)d_out;

  char* ws = (char*)d_ws;
  size_t off = 0;
  auto alloc = [&](size_t bytes) {
    char* p = ws + off;
    off += (bytes + 255) & ~(size_t)255;
    return p;
  };
  f16* hb = (f16*)alloc(4096ull * 1024 * 2);
  f16* wqb = (f16*)alloc(2048ull * 1024 * 2);
  f16* wkb = (f16*)alloc(1024ull * 1024 * 2);
  f16* wvb = (f16*)alloc(1024ull * 1024 * 2);
  f16* wob = (f16*)alloc(1024ull * 2048 * 2);
  float* qf = (float*)alloc(4096ull * 2048 * 4);
  float* kf = (float*)alloc(4096ull * 1024 * 4);
  float* vf = (float*)alloc(4096ull * 1024 * 4);
  f16* qt = (f16*)alloc(32ull * 2048 * 128 * 2);
  f16* kt = (f16*)alloc(16ull * 2048 * 128 * 2);
  f16* vt = (f16*)alloc(16ull * 2048 * 128 * 2);
  f16* ot = (f16*)alloc(4096ull * 2048 * 2);

  cast_f32_f16<<<4096, 256, 0, stream>>>(hidden, hb, 4194304);
  cast_f32_f16<<<2048, 256, 0, stream>>>(Wq, wqb, 2097152);
  cast_f32_f16<<<1024, 256, 0, stream>>>(Wk, wkb, 1048576);
  cast_f32_f16<<<1024, 256, 0, stream>>>(Wv, wvb, 1048576);
  cast_f32_f16<<<2048, 256, 0, stream>>>(Wo, wob, 2097152);

  gemm_bt<<<dim3(16, 32), 256, 0, stream>>>(hb, wqb, qf, 4096, 2048, 1024);
  gemm_bt<<<dim3(8, 32), 256, 0, stream>>>(hb, wkb, kf, 4096, 1024, 1024);
  gemm_bt<<<dim3(8, 32), 256, 0, stream>>>(hb, wvb, vf, 4096, 1024, 1024);

  rope_norm<<<24576, 256, 0, stream>>>(qf, kf, cosT, sinT, qnw, knw, qt, kt);
  v_transpose<<<dim3(32, 16), 256, 0, stream>>>(vf, vt);

  attn<<<dim3(32, 32), 256, 0, stream>>>(qt, kt, vt, ot);

  gemm_bt<<<dim3(8, 32), 256, 0, stream>>>(ot, wob, out, 4096, 1024, 2048);
}

// Round 2
// 376.570 us; speedup vs baseline: 1.5783x; 1.5783x over previous
//
#include <hip/hip_runtime.h>
#include <hip/hip_fp16.h>

// Qwen3 attention block: B=2 S=2048 HID=1024 NH=16 NKV=8 HD=128, causal.
// f16-MFMA pipeline, fp32 accumulate.
// R2: attn rewritten (K-tile 64, paired q-tiles for balance, padded LDS,
//     lane-partial l, wave-local P sync, XCD swizzle); gemm_bt uses
//     global_load_lds width-16 staging.

typedef _Float16 f16;
typedef __attribute__((ext_vector_type(8))) _Float16 f16x8;
typedef __attribute__((ext_vector_type(4))) _Float16 f16x4;
typedef __attribute__((ext_vector_type(4))) float f32x4;

__constant__ const float kEps = 1e-6f;
__constant__ const float kScale = 0.08838834764831845f;  // 1/sqrt(128), folded into Q

// async global->LDS, 16B per lane; lds dest must be wave-uniform base (+lane*16)
#define ASYNC_LD16(gp, lp)                                              \
  __builtin_amdgcn_global_load_lds(                                     \
      (const __attribute__((address_space(1))) void*)(gp),              \
      (__attribute__((address_space(3))) void*)(uint32_t)(uintptr_t)(lp), 16, 0, 0)

// ---------------------------------------------------------------- cast f32->f16
__global__ __launch_bounds__(256) void cast_f32_f16(const float* __restrict__ in,
                                                    f16* __restrict__ out, int n) {
  int i = (blockIdx.x * 256 + threadIdx.x) * 4;
  if (i >= n) return;
  f32x4 v = *reinterpret_cast<const f32x4*>(in + i);
  f16x4 o;
  o.x = (f16)v.x; o.y = (f16)v.y; o.z = (f16)v.z; o.w = (f16)v.w;
  *reinterpret_cast<f16x4*>(out + i) = o;
}

// ------------------------------------------------- C[M,N] = A[M,K] * B[N,K]^T
// 128x128 tile, BK=32, 4 waves each owning 64x64 (4x4 of 16x16x32 MFMA).
// Staging via global_load_lds: LDS layout is exactly tid*16 B (lane-contiguous).
__global__ __launch_bounds__(256) void gemm_bt(const f16* __restrict__ A,
                                               const f16* __restrict__ Bm,
                                               float* __restrict__ C,
                                               int M, int N, int K) {
  __shared__ __align__(16) f16 As[128][32];
  __shared__ __align__(16) f16 Bs[128][32];
  const int tid = threadIdx.x;
  const int lane = tid & 63;
  const int wave = tid >> 6;
  const int cl = lane & 15;
  const int quad = lane >> 4;
  const int wm = (wave >> 1) * 64;
  const int wn = (wave & 1) * 64;
  const int tm = blockIdx.y * 128;
  const int tn = blockIdx.x * 128;
  const int r0 = tid >> 2;          // staging row 0..63
  const int c0 = (tid & 3) * 8;     // staging col offset (elements)

  const f16* Ab = A + (size_t)(tm + r0) * K + c0;
  const f16* Bb = Bm + (size_t)(tn + r0) * K + c0;
  char* Albase = (char*)As + wave * 1024;   // wave-uniform
  char* Blbase = (char*)Bs + wave * 1024;

  f32x4 acc[4][4] = {};

  for (int k0 = 0; k0 < K; k0 += 32) {
    ASYNC_LD16(Ab + k0, Albase);
    ASYNC_LD16(Ab + (size_t)64 * K + k0, Albase + 4096);
    ASYNC_LD16(Bb + k0, Blbase);
    ASYNC_LD16(Bb + (size_t)64 * K + k0, Blbase + 4096);
    __syncthreads();
    f16x8 af[4], bf[4];
#pragma unroll
    for (int mi = 0; mi < 4; ++mi)
      af[mi] = *reinterpret_cast<const f16x8*>(&As[wm + mi * 16 + cl][quad * 8]);
#pragma unroll
    for (int ni = 0; ni < 4; ++ni)
      bf[ni] = *reinterpret_cast<const f16x8*>(&Bs[wn + ni * 16 + cl][quad * 8]);
#pragma unroll
    for (int mi = 0; mi < 4; ++mi)
#pragma unroll
      for (int ni = 0; ni < 4; ++ni)
        acc[mi][ni] =
            __builtin_amdgcn_mfma_f32_16x16x32_f16(af[mi], bf[ni], acc[mi][ni], 0, 0, 0);
    __syncthreads();
  }
  // C/D layout (verified): col = lane&15, row = quad*4 + reg
#pragma unroll
  for (int mi = 0; mi < 4; ++mi)
#pragma unroll
    for (int ni = 0; ni < 4; ++ni)
#pragma unroll
      for (int r = 0; r < 4; ++r)
        C[(size_t)(tm + wm + mi * 16 + quad * 4 + r) * N + tn + wn + ni * 16 + cl] =
            acc[mi][ni][r];
}

// -------------------------- RMSNorm + RoPE + transpose for Q,K (wave per row)
__global__ __launch_bounds__(256) void rope_norm(
    const float* __restrict__ qf, const float* __restrict__ kf,
    const float* __restrict__ cosT, const float* __restrict__ sinT,
    const float* __restrict__ qw, const float* __restrict__ kw,
    f16* __restrict__ qt, f16* __restrict__ kt) {
  const int gw = blockIdx.x * 4 + (threadIdx.x >> 6);
  const int lane = threadIdx.x & 63;
  const int head = gw % 24;
  const int bs = gw / 24;
  const bool isq = head < 16;
  const float* src = isq ? qf + (size_t)bs * 2048 + head * 128
                         : kf + (size_t)bs * 1024 + (head - 16) * 128;
  const float x1 = src[lane];
  const float x2 = src[lane + 64];
  float ss = x1 * x1 + x2 * x2;
#pragma unroll
  for (int off = 32; off >= 1; off >>= 1) ss += __shfl_xor(ss, off);
  const float rms = rsqrtf(ss * (1.0f / 128.0f) + kEps);
  const float* w = isq ? qw : kw;
  const float n1 = x1 * rms * w[lane];
  const float n2 = x2 * rms * w[lane + 64];
  const float* cb = cosT + (size_t)bs * 128;
  const float* sb = sinT + (size_t)bs * 128;
  const float o1 = n1 * cb[lane] - n2 * sb[lane];
  const float o2 = n2 * cb[lane + 64] + n1 * sb[lane + 64];
  const int b = bs >> 11;
  const int s = bs & 2047;
  f16* dst;
  float sc;
  if (isq) {
    dst = qt + ((size_t)(b * 16 + head) * 2048 + s) * 128;
    sc = kScale;
  } else {
    dst = kt + ((size_t)(b * 8 + (head - 16)) * 2048 + s) * 128;
    sc = 1.0f;
  }
  dst[lane] = (f16)(o1 * sc);
  dst[lane + 64] = (f16)(o2 * sc);
}

// ------------------------------- V: (B*S, NKV*HD) fp32 -> (B*NKV, HD, S) f16
__global__ __launch_bounds__(256) void v_transpose(const float* __restrict__ vf,
                                                   f16* __restrict__ vt) {
  __shared__ f16 tile[64][136];
  const int bh = blockIdx.y;
  const int b = bh >> 3, h = bh & 7;
  const int s0 = blockIdx.x * 64;
  const int tid = threadIdx.x;
#pragma unroll
  for (int i = 0; i < 8; ++i) {
    int c = tid + i * 256;
    int s = c >> 5;
    int d0 = (c & 31) * 4;
    f32x4 v = *reinterpret_cast<const f32x4*>(
        vf + (size_t)(b * 2048 + s0 + s) * 1024 + h * 128 + d0);
    tile[s][d0 + 0] = (f16)v.x;
    tile[s][d0 + 1] = (f16)v.y;
    tile[s][d0 + 2] = (f16)v.z;
    tile[s][d0 + 3] = (f16)v.w;
  }
  __syncthreads();
#pragma unroll
  for (int i = 0; i < 4; ++i) {
    int c = tid + i * 256;
    int d = c >> 3;
    int sB = (c & 7) * 8;
    f16x8 o;
#pragma unroll
    for (int j = 0; j < 8; ++j) o[j] = tile[sB + j][d];
    *reinterpret_cast<f16x8*>(vt + ((size_t)(b * 8 + h) * 128 + d) * 2048 + s0 + sB) = o;
  }
}

// ------------------------------------------------------- flash attention (causal)
// 512 blocks; block handles q-tiles {31-pair, pair} of one (b,h) -> 33 k-iters
// each (perfect balance). K-tile 64. 4 waves, each owns 16 q-rows x full 64 k.
__global__ __launch_bounds__(256) void attn(const f16* __restrict__ Qt,
                                            const f16* __restrict__ Kt,
                                            const f16* __restrict__ Vt,
                                            f16* __restrict__ Ot) {
  __shared__ __align__(16) f16 Ks[64][136];   // k-rows x d   (stride 272B = 4 banks mod 32)
  __shared__ __align__(16) f16 Vs[128][72];   // d x k-rows   (stride 144B = 4 banks mod 32)
  __shared__ __align__(16) f16 Ps[4][16][72]; // per-wave P:  C-layout -> A-layout round-trip

  // XCD swizzle: all 32 blocks of one (b,kv) land on one XCD (id%8 heuristic)
  const int lid = blockIdx.x;
  const int bkv = (lid & 7) | (((lid >> 3) & 1) << 3);  // 0..15
  const int rem = lid >> 4;                              // 0..31
  const int hq = rem & 1;
  const int pair = rem >> 1;                             // 0..15
  const int b = bkv >> 3, kv = bkv & 7;
  const int h = kv * 2 + hq;
  const int bh = b * 16 + h;

  const int tid = threadIdx.x;
  const int lane = tid & 63, wv = tid >> 6;
  const int cl = lane & 15, quad = lane >> 4;

  const f16* kbase = Kt + (size_t)(b * 8 + kv) * 2048 * 128;
  const f16* vbase = Vt + (size_t)(b * 8 + kv) * 128 * 2048;

#pragma unroll 1
  for (int t = 0; t < 2; ++t) {
    const int qt = (t == 0) ? (31 - pair) : pair;
    const int q0 = qt * 64;

    const f16* qbase = Qt + ((size_t)bh * 2048 + q0 + wv * 16 + cl) * 128;
    f16x8 aq[4];
#pragma unroll
    for (int kk = 0; kk < 4; ++kk)
      aq[kk] = *reinterpret_cast<const f16x8*>(qbase + kk * 32 + quad * 8);

    float m_r[4], l_r[4];
#pragma unroll
    for (int r = 0; r < 4; ++r) { m_r[r] = -1e30f; l_r[r] = 0.f; }
    f32x4 oacc[8] = {};
    const int qg_base = q0 + wv * 16 + quad * 4;

    for (int kt0 = 0; kt0 <= q0; kt0 += 64) {
      // ---- stage K (64x128) and V (128x64) : 1024+1024 16B chunks
#pragma unroll
      for (int i = 0; i < 4; ++i) {
        int c = tid + i * 256;
        int krow = c >> 4, d0 = (c & 15) * 8;
        *reinterpret_cast<int4*>(&Ks[krow][d0]) =
            *reinterpret_cast<const int4*>(kbase + (size_t)(kt0 + krow) * 128 + d0);
        int dr = c >> 3, ko = (c & 7) * 8;
        *reinterpret_cast<int4*>(&Vs[dr][ko]) =
            *reinterpret_cast<const int4*>(vbase + (size_t)dr * 2048 + kt0 + ko);
      }
      __syncthreads();
      // ---- QK^T : 16 MFMAs -> sacc[ni], rows quad*4+r, cols kt0+ni*16+cl
      f32x4 sacc[4] = {};
#pragma unroll
      for (int kk = 0; kk < 4; ++kk)
#pragma unroll
        for (int ni = 0; ni < 4; ++ni) {
          f16x8 bk = *reinterpret_cast<const f16x8*>(&Ks[ni * 16 + cl][kk * 32 + quad * 8]);
          sacc[ni] = __builtin_amdgcn_mfma_f32_16x16x32_f16(aq[kk], bk, sacc[ni], 0, 0, 0);
        }
      // ---- causal mask only on the diagonal tile
      if (kt0 == q0) {
#pragma unroll
        for (int ni = 0; ni < 4; ++ni) {
          const int kg = kt0 + ni * 16 + cl;
#pragma unroll
          for (int r = 0; r < 4; ++r)
            if (kg > qg_base + r) sacc[ni][r] = -1e30f;
        }
      }
      // ---- online softmax; l stays lane-partial (no per-iter sum shuffle)
      float mx[4], al[4];
#pragma unroll
      for (int r = 0; r < 4; ++r)
        mx[r] = fmaxf(fmaxf(sacc[0][r], sacc[1][r]), fmaxf(sacc[2][r], sacc[3][r]));
#pragma unroll
      for (int off = 1; off < 16; off <<= 1)
#pragma unroll
        for (int r = 0; r < 4; ++r) mx[r] = fmaxf(mx[r], __shfl_xor(mx[r], off));
#pragma unroll
      for (int r = 0; r < 4; ++r) {
        const float nm = fmaxf(m_r[r], mx[r]);
        al[r] = __expf(m_r[r] - nm);
        m_r[r] = nm;
        float ps = 0.f;
#pragma unroll
        for (int ni = 0; ni < 4; ++ni) {
          const float p = __expf(sacc[ni][r] - nm);
          sacc[ni][r] = p;
          ps += p;
        }
        l_r[r] = l_r[r] * al[r] + ps;
      }
      // ---- P to LDS (C-layout write), wave-local visibility only
#pragma unroll
      for (int ni = 0; ni < 4; ++ni)
#pragma unroll
        for (int r = 0; r < 4; ++r)
          Ps[wv][quad * 4 + r][ni * 16 + cl] = (f16)sacc[ni][r];
#pragma unroll
      for (int dg = 0; dg < 8; ++dg)
#pragma unroll
        for (int r = 0; r < 4; ++r) oacc[dg][r] *= al[r];
      asm volatile("s_waitcnt lgkmcnt(0)" ::: "memory");  // Ps is per-wave: no barrier
      // ---- PV : A-layout read of P, 16 MFMAs
      f16x8 ap0 = *reinterpret_cast<const f16x8*>(&Ps[wv][cl][quad * 8]);
      f16x8 ap1 = *reinterpret_cast<const f16x8*>(&Ps[wv][cl][32 + quad * 8]);
#pragma unroll
      for (int dg = 0; dg < 8; ++dg) {
        f16x8 bv0 = *reinterpret_cast<const f16x8*>(&Vs[dg * 16 + cl][quad * 8]);
        oacc[dg] = __builtin_amdgcn_mfma_f32_16x16x32_f16(ap0, bv0, oacc[dg], 0, 0, 0);
        f16x8 bv1 = *reinterpret_cast<const f16x8*>(&Vs[dg * 16 + cl][32 + quad * 8]);
        oacc[dg] = __builtin_amdgcn_mfma_f32_16x16x32_f16(ap1, bv1, oacc[dg], 0, 0, 0);
      }
      __syncthreads();  // protect Ks/Vs before next stage
    }
    // ---- finalize: reduce lane-partial l across the 16 cols, write O
#pragma unroll
    for (int off = 1; off < 16; off <<= 1)
#pragma unroll
      for (int r = 0; r < 4; ++r) l_r[r] += __shfl_xor(l_r[r], off);
#pragma unroll
    for (int r = 0; r < 4; ++r) {
      const int qg = qg_base + r;
      const float inv = 1.0f / l_r[r];
#pragma unroll
      for (int dg = 0; dg < 8; ++dg)
        Ot[(size_t)(b * 2048 + qg) * 2048 + h * 128 + dg * 16 + cl] =
            (f16)(oacc[dg][r] * inv);
    }
  }
}

// ---------------------------------------------------------------------- launch
extern "C" void kernel_launch(void* const* d_in, const int* in_sizes, int n_in,
                              void* d_out, int out_size, void* d_ws, size_t ws_size,
                              hipStream_t stream) {
  (void)in_sizes; (void)n_in; (void)out_size; (void)ws_size;
  const float* hidden = (const float*)d_in[0];
  const float* cosT = (const float*)d_in[1];
  const float* sinT = (const float*)d_in[2];
  // d_in[3] = attention_mask: exactly causal triu * -1e9 -> computed analytically
  const float* Wq = (const float*)d_in[4];
  const float* Wk = (const float*)d_in[5];
  const float* Wv = (const float*)d_in[6];
  const float* Wo = (const float*)d_in[7];
  const float* qnw = (const float*)d_in[8];
  const float* knw = (const float*)d_in[9];
  float* out = (float*)d_out;

  char* ws = (char*)d_ws;
  size_t off = 0;
  auto alloc = [&](size_t bytes) {
    char* p = ws + off;
    off += (bytes + 255) & ~(size_t)255;
    return p;
  };
  f16* hb = (f16*)alloc(4096ull * 1024 * 2);
  f16* wqb = (f16*)alloc(2048ull * 1024 * 2);
  f16* wkb = (f16*)alloc(1024ull * 1024 * 2);
  f16* wvb = (f16*)alloc(1024ull * 1024 * 2);
  f16* wob = (f16*)alloc(1024ull * 2048 * 2);
  float* qf = (float*)alloc(4096ull * 2048 * 4);
  float* kf = (float*)alloc(4096ull * 1024 * 4);
  float* vf = (float*)alloc(4096ull * 1024 * 4);
  f16* qt = (f16*)alloc(32ull * 2048 * 128 * 2);
  f16* kt = (f16*)alloc(16ull * 2048 * 128 * 2);
  f16* vt = (f16*)alloc(16ull * 2048 * 128 * 2);
  f16* ot = (f16*)alloc(4096ull * 2048 * 2);

  cast_f32_f16<<<4096, 256, 0, stream>>>(hidden, hb, 4194304);
  cast_f32_f16<<<2048, 256, 0, stream>>>(Wq, wqb, 2097152);
  cast_f32_f16<<<1024, 256, 0, stream>>>(Wk, wkb, 1048576);
  cast_f32_f16<<<1024, 256, 0, stream>>>(Wv, wvb, 1048576);
  cast_f32_f16<<<2048, 256, 0, stream>>>(Wo, wob, 2097152);

  gemm_bt<<<dim3(16, 32), 256, 0, stream>>>(hb, wqb, qf, 4096, 2048, 1024);
  gemm_bt<<<dim3(8, 32), 256, 0, stream>>>(hb, wkb, kf, 4096, 1024, 1024);
  gemm_bt<<<dim3(8, 32), 256, 0, stream>>>(hb, wvb, vf, 4096, 1024, 1024);

  rope_norm<<<24576, 256, 0, stream>>>(qf, kf, cosT, sinT, qnw, knw, qt, kt);
  v_transpose<<<dim3(32, 16), 256, 0, stream>>>(vf, vt);

  attn<<<512, 256, 0, stream>>>(qt, kt, vt, ot);

  gemm_bt<<<dim3(8, 32), 256, 0, stream>>>(ot, wob, out, 4096, 1024, 2048);
}

// Round 3
// 326.183 us; speedup vs baseline: 1.8221x; 1.1545x over previous
//
#include <hip/hip_runtime.h>
#include <hip/hip_fp16.h>

// Qwen3 attention block: B=2 S=2048 HID=1024 NH=16 NKV=8 HD=128, causal.
// R3: gemm BK=64 + XOR-swizzle (conflict-free with async staging), fused QKV
//     gemm (N=4096); attn q=32/wave 2-wave blocks, DPP max, exp2 softmax.

typedef _Float16 f16;
typedef __attribute__((ext_vector_type(8))) _Float16 f16x8;
typedef __attribute__((ext_vector_type(4))) _Float16 f16x4;
typedef __attribute__((ext_vector_type(4))) float f32x4;

__constant__ const float kEps = 1e-6f;
// 1/sqrt(128) * log2(e): Q pre-scaled so attn softmax runs in exp2 domain
__constant__ const float kScaleL2 = 0.1275179120685481f;

// async global->LDS, 16B/lane; lds ptr must be wave-uniform (HW adds lane*16)
#define ASYNC_LD16(gp, lp)                                              \
  __builtin_amdgcn_global_load_lds(                                     \
      (const __attribute__((address_space(1))) void*)(gp),              \
      (__attribute__((address_space(3))) void*)(uint32_t)(uintptr_t)(lp), 16, 0, 0)

// max/sum reduce across the 16 lanes of a DPP row (our cl group)
__device__ __forceinline__ float dpp_max16(float v) {
  int x;
  x = __builtin_amdgcn_update_dpp(0, __builtin_bit_cast(int, v), 0xB1, 0xF, 0xF, true);
  v = fmaxf(v, __builtin_bit_cast(float, x));  // quad_perm xor1
  x = __builtin_amdgcn_update_dpp(0, __builtin_bit_cast(int, v), 0x4E, 0xF, 0xF, true);
  v = fmaxf(v, __builtin_bit_cast(float, x));  // quad_perm xor2
  x = __builtin_amdgcn_update_dpp(0, __builtin_bit_cast(int, v), 0x141, 0xF, 0xF, true);
  v = fmaxf(v, __builtin_bit_cast(float, x));  // row_half_mirror (8-group)
  x = __builtin_amdgcn_update_dpp(0, __builtin_bit_cast(int, v), 0x140, 0xF, 0xF, true);
  v = fmaxf(v, __builtin_bit_cast(float, x));  // row_mirror (16-group)
  return v;
}
__device__ __forceinline__ float dpp_sum16(float v) {
  int x;
  x = __builtin_amdgcn_update_dpp(0, __builtin_bit_cast(int, v), 0xB1, 0xF, 0xF, true);
  v += __builtin_bit_cast(float, x);
  x = __builtin_amdgcn_update_dpp(0, __builtin_bit_cast(int, v), 0x4E, 0xF, 0xF, true);
  v += __builtin_bit_cast(float, x);
  x = __builtin_amdgcn_update_dpp(0, __builtin_bit_cast(int, v), 0x141, 0xF, 0xF, true);
  v += __builtin_bit_cast(float, x);
  x = __builtin_amdgcn_update_dpp(0, __builtin_bit_cast(int, v), 0x140, 0xF, 0xF, true);
  v += __builtin_bit_cast(float, x);
  return v;
}

// ---------------------------------------------------------------- cast f32->f16
__global__ __launch_bounds__(256) void cast_f32_f16(const float* __restrict__ in,
                                                    f16* __restrict__ out, int n) {
  int i = (blockIdx.x * 256 + threadIdx.x) * 4;
  if (i >= n) return;
  f32x4 v = *reinterpret_cast<const f32x4*>(in + i);
  f16x4 o;
  o.x = (f16)v.x; o.y = (f16)v.y; o.z = (f16)v.z; o.w = (f16)v.w;
  *reinterpret_cast<f16x4*>(out + i) = o;
}

// ------------------------------------------------- C[M,N] = A[M,K] * B[N,K]^T
// 128x128 tile, BK=64, XOR-swizzled LDS (conflict-free frag reads while
// keeping global_load_lds lane-contiguous deposit: per-lane global col is
// permuted so stored colgroup g' holds global group g = g' ^ (row&7)).
__global__ __launch_bounds__(256) void gemm_bt(const f16* __restrict__ A,
                                               const f16* __restrict__ Bm,
                                               float* __restrict__ C,
                                               int M, int N, int K) {
  __shared__ __align__(16) f16 As[128][64];
  __shared__ __align__(16) f16 Bs[128][64];
  const int tid = threadIdx.x;
  const int lane = tid & 63;
  const int wave = tid >> 6;
  const int cl = lane & 15;
  const int quad = lane >> 4;
  const int wm = (wave >> 1) * 64;
  const int wn = (wave & 1) * 64;
  const int tm = blockIdx.y * 128;
  const int tn = blockIdx.x * 128;
  const int r0 = tid >> 3;                       // staging row 0..31 (per chunk)
  const int csw = ((tid & 7) ^ (r0 & 7)) * 8;    // swizzled global col

  const f16* Ab = A + (size_t)(tm + r0) * K + csw;
  const f16* Bb = Bm + (size_t)(tn + r0) * K + csw;
  char* Al = (char*)As + wave * 1024;            // wave-uniform LDS base
  char* Bl = (char*)Bs + wave * 1024;

  f32x4 acc[4][4] = {};

  for (int k0 = 0; k0 < K; k0 += 64) {
#pragma unroll
    for (int c = 0; c < 4; ++c) {
      ASYNC_LD16(Ab + (size_t)(c * 32) * K + k0, Al + c * 4096);
      ASYNC_LD16(Bb + (size_t)(c * 32) * K + k0, Bl + c * 4096);
    }
    __syncthreads();
#pragma unroll
    for (int kk = 0; kk < 2; ++kk) {
      f16x8 af[4], bf[4];
#pragma unroll
      for (int mi = 0; mi < 4; ++mi)
        af[mi] = *reinterpret_cast<const f16x8*>(
            &As[wm + mi * 16 + cl][((kk * 4 + quad) ^ (cl & 7)) * 8]);
#pragma unroll
      for (int ni = 0; ni < 4; ++ni)
        bf[ni] = *reinterpret_cast<const f16x8*>(
            &Bs[wn + ni * 16 + cl][((kk * 4 + quad) ^ (cl & 7)) * 8]);
#pragma unroll
      for (int mi = 0; mi < 4; ++mi)
#pragma unroll
        for (int ni = 0; ni < 4; ++ni)
          acc[mi][ni] =
              __builtin_amdgcn_mfma_f32_16x16x32_f16(af[mi], bf[ni], acc[mi][ni], 0, 0, 0);
    }
    __syncthreads();
  }
  // C/D layout: col = lane&15, row = quad*4 + reg
#pragma unroll
  for (int mi = 0; mi < 4; ++mi)
#pragma unroll
    for (int ni = 0; ni < 4; ++ni)
#pragma unroll
      for (int r = 0; r < 4; ++r)
        C[(size_t)(tm + wm + mi * 16 + quad * 4 + r) * N + tn + wn + ni * 16 + cl] =
            acc[mi][ni][r];
}

// -------------------------- RMSNorm + RoPE + transpose for Q,K (wave per row)
// qkvf: (B*S, 4096) fp32 fused [Q 0..2047 | K 2048..3071 | V 3072..4095]
__global__ __launch_bounds__(256) void rope_norm(
    const float* __restrict__ qkvf,
    const float* __restrict__ cosT, const float* __restrict__ sinT,
    const float* __restrict__ qw, const float* __restrict__ kw,
    f16* __restrict__ qt, f16* __restrict__ kt) {
  const int gw = blockIdx.x * 4 + (threadIdx.x >> 6);
  const int lane = threadIdx.x & 63;
  const int head = gw % 24;
  const int bs = gw / 24;
  const bool isq = head < 16;
  const float* src = qkvf + (size_t)bs * 4096 +
                     (isq ? head * 128 : 2048 + (head - 16) * 128);
  const float x1 = src[lane];
  const float x2 = src[lane + 64];
  float ss = x1 * x1 + x2 * x2;
#pragma unroll
  for (int off = 32; off >= 1; off >>= 1) ss += __shfl_xor(ss, off);
  const float rms = rsqrtf(ss * (1.0f / 128.0f) + kEps);
  const float* w = isq ? qw : kw;
  const float n1 = x1 * rms * w[lane];
  const float n2 = x2 * rms * w[lane + 64];
  const float* cb = cosT + (size_t)bs * 128;
  const float* sb = sinT + (size_t)bs * 128;
  const float o1 = n1 * cb[lane] - n2 * sb[lane];
  const float o2 = n2 * cb[lane + 64] + n1 * sb[lane + 64];
  const int b = bs >> 11;
  const int s = bs & 2047;
  f16* dst;
  float sc;
  if (isq) {
    dst = qt + ((size_t)(b * 16 + head) * 2048 + s) * 128;
    sc = kScaleL2;  // 1/sqrt(128) * log2e
  } else {
    dst = kt + ((size_t)(b * 8 + (head - 16)) * 2048 + s) * 128;
    sc = 1.0f;
  }
  dst[lane] = (f16)(o1 * sc);
  dst[lane + 64] = (f16)(o2 * sc);
}

// ------------------------------- V slice of qkvf fp32 -> (B*NKV, HD, S) f16
__global__ __launch_bounds__(256) void v_transpose(const float* __restrict__ qkvf,
                                                   f16* __restrict__ vt) {
  __shared__ f16 tile[64][136];
  const int bh = blockIdx.y;
  const int b = bh >> 3, h = bh & 7;
  const int s0 = blockIdx.x * 64;
  const int tid = threadIdx.x;
#pragma unroll
  for (int i = 0; i < 8; ++i) {
    int c = tid + i * 256;
    int s = c >> 5;
    int d0 = (c & 31) * 4;
    f32x4 v = *reinterpret_cast<const f32x4*>(
        qkvf + (size_t)(b * 2048 + s0 + s) * 4096 + 3072 + h * 128 + d0);
    tile[s][d0 + 0] = (f16)v.x;
    tile[s][d0 + 1] = (f16)v.y;
    tile[s][d0 + 2] = (f16)v.z;
    tile[s][d0 + 3] = (f16)v.w;
  }
  __syncthreads();
#pragma unroll
  for (int i = 0; i < 4; ++i) {
    int c = tid + i * 256;
    int d = c >> 3;
    int sB = (c & 7) * 8;
    f16x8 o;
#pragma unroll
    for (int j = 0; j < 8; ++j) o[j] = tile[sB + j][d];
    *reinterpret_cast<f16x8*>(vt + ((size_t)(b * 8 + h) * 128 + d) * 2048 + s0 + sB) = o;
  }
}

// ------------------------------------------------------- flash attention (causal)
// 1024 blocks of 128 threads (2 waves), each wave owns 32 q-rows; K-tile 64.
// Longest q-tiles dispatched first; bh = bid&31 groups a (b,kv)'s blocks on
// one XCD (bid%8 heuristic). Scores in exp2 domain (Q pre-scaled by log2e).
__global__ __launch_bounds__(128) void attn(const f16* __restrict__ Qt,
                                            const f16* __restrict__ Kt,
                                            const f16* __restrict__ Vt,
                                            f16* __restrict__ Ot) {
  __shared__ __align__(16) f16 Ks[64][136];   // stride 272B = 4 banks mod 32
  __shared__ __align__(16) f16 Vs[128][72];   // stride 144B = 4 banks mod 32
  __shared__ __align__(16) f16 Ps[2][32][72]; // per-wave P round-trip

  const int bid = blockIdx.x;
  const int bh = bid & 31;
  const int t = 31 - (bid >> 5);   // longest tiles first
  const int q0 = t * 64;
  const int b = bh >> 4, h = bh & 15;
  const int kv = h >> 1;

  const int tid = threadIdx.x;
  const int lane = tid & 63, wv = tid >> 6;
  const int cl = lane & 15, quad = lane >> 4;

  const f16* qbase = Qt + ((size_t)(b * 16 + h) * 2048 + q0 + wv * 32 + cl) * 128;
  f16x8 aq[2][4];
#pragma unroll
  for (int mi = 0; mi < 2; ++mi)
#pragma unroll
    for (int kk = 0; kk < 4; ++kk)
      aq[mi][kk] =
          *reinterpret_cast<const f16x8*>(qbase + mi * 16 * 128 + kk * 32 + quad * 8);

  const f16* kbase = Kt + (size_t)(b * 8 + kv) * 2048 * 128;
  const f16* vbase = Vt + (size_t)(b * 8 + kv) * 128 * 2048;

  float m_[2][4], l_[2][4];
#pragma unroll
  for (int mi = 0; mi < 2; ++mi)
#pragma unroll
    for (int r = 0; r < 4; ++r) { m_[mi][r] = -1e30f; l_[mi][r] = 0.f; }
  f32x4 oacc[2][8] = {};

  for (int kt0 = 0; kt0 <= q0; kt0 += 64) {
    // ---- stage K (64x128) and V (128x64): 1024+1024 16B chunks, 128 threads
#pragma unroll
    for (int i = 0; i < 8; ++i) {
      int c = tid + i * 128;
      int krow = c >> 4, d0 = (c & 15) * 8;
      *reinterpret_cast<int4*>(&Ks[krow][d0]) =
          *reinterpret_cast<const int4*>(kbase + (size_t)(kt0 + krow) * 128 + d0);
      int dr = c >> 3, ko = (c & 7) * 8;
      *reinterpret_cast<int4*>(&Vs[dr][ko]) =
          *reinterpret_cast<const int4*>(vbase + (size_t)dr * 2048 + kt0 + ko);
    }
    __syncthreads();
    // ---- QK^T: 32 MFMAs, 16 K-frag loads (reused across mi)
    f32x4 sacc[2][4] = {};
#pragma unroll
    for (int kk = 0; kk < 4; ++kk)
#pragma unroll
      for (int ni = 0; ni < 4; ++ni) {
        f16x8 bk = *reinterpret_cast<const f16x8*>(&Ks[ni * 16 + cl][kk * 32 + quad * 8]);
#pragma unroll
        for (int mi = 0; mi < 2; ++mi)
          sacc[mi][ni] =
              __builtin_amdgcn_mfma_f32_16x16x32_f16(aq[mi][kk], bk, sacc[mi][ni], 0, 0, 0);
      }
    // ---- causal mask (diagonal k-tile only)
    if (kt0 == q0) {
#pragma unroll
      for (int mi = 0; mi < 2; ++mi) {
        const int qr = wv * 32 + mi * 16 + quad * 4;
#pragma unroll
        for (int ni = 0; ni < 4; ++ni) {
          const int kg = ni * 16 + cl;
#pragma unroll
          for (int r = 0; r < 4; ++r)
            if (kg > qr + r) sacc[mi][ni][r] = -1e30f;
        }
      }
    }
    // ---- online softmax (exp2 domain); l lane-partial; DPP max off LDS pipe
    float alv[2][4];
#pragma unroll
    for (int mi = 0; mi < 2; ++mi)
#pragma unroll
      for (int r = 0; r < 4; ++r) {
        float mx = fmaxf(fmaxf(sacc[mi][0][r], sacc[mi][1][r]),
                         fmaxf(sacc[mi][2][r], sacc[mi][3][r]));
        mx = dpp_max16(mx);
        const float nm = fmaxf(m_[mi][r], mx);
        const float al = __builtin_amdgcn_exp2f(m_[mi][r] - nm);
        m_[mi][r] = nm;
        float ps = 0.f;
#pragma unroll
        for (int ni = 0; ni < 4; ++ni) {
          const float p = __builtin_amdgcn_exp2f(sacc[mi][ni][r] - nm);
          sacc[mi][ni][r] = p;
          ps += p;
        }
        l_[mi][r] = l_[mi][r] * al + ps;
        alv[mi][r] = al;
      }
    // ---- P to LDS (C-layout), rescale O, wave-local sync, PV
#pragma unroll
    for (int mi = 0; mi < 2; ++mi)
#pragma unroll
      for (int ni = 0; ni < 4; ++ni)
#pragma unroll
        for (int r = 0; r < 4; ++r)
          Ps[wv][mi * 16 + quad * 4 + r][ni * 16 + cl] = (f16)sacc[mi][ni][r];
#pragma unroll
    for (int mi = 0; mi < 2; ++mi)
#pragma unroll
      for (int dg = 0; dg < 8; ++dg)
#pragma unroll
        for (int r = 0; r < 4; ++r) oacc[mi][dg][r] *= alv[mi][r];
    asm volatile("s_waitcnt lgkmcnt(0)" ::: "memory");  // Ps is per-wave
    f16x8 ap[2][2];
#pragma unroll
    for (int mi = 0; mi < 2; ++mi)
#pragma unroll
      for (int kh = 0; kh < 2; ++kh)
        ap[mi][kh] =
            *reinterpret_cast<const f16x8*>(&Ps[wv][mi * 16 + cl][kh * 32 + quad * 8]);
#pragma unroll
    for (int kh = 0; kh < 2; ++kh)
#pragma unroll
      for (int dg = 0; dg < 8; ++dg) {
        f16x8 bv = *reinterpret_cast<const f16x8*>(&Vs[dg * 16 + cl][kh * 32 + quad * 8]);
#pragma unroll
        for (int mi = 0; mi < 2; ++mi)
          oacc[mi][dg] =
              __builtin_amdgcn_mfma_f32_16x16x32_f16(ap[mi][kh], bv, oacc[mi][dg], 0, 0, 0);
      }
    __syncthreads();  // protect Ks/Vs before next stage
  }
  // ---- finalize: reduce lane-partial l across cl (DPP), write O
#pragma unroll
  for (int mi = 0; mi < 2; ++mi)
#pragma unroll
    for (int r = 0; r < 4; ++r) {
      const float inv = 1.0f / dpp_sum16(l_[mi][r]);
      const int qg = q0 + wv * 32 + mi * 16 + quad * 4 + r;
#pragma unroll
      for (int dg = 0; dg < 8; ++dg)
        Ot[(size_t)(b * 2048 + qg) * 2048 + h * 128 + dg * 16 + cl] =
            (f16)(oacc[mi][dg][r] * inv);
    }
}

// ---------------------------------------------------------------------- launch
extern "C" void kernel_launch(void* const* d_in, const int* in_sizes, int n_in,
                              void* d_out, int out_size, void* d_ws, size_t ws_size,
                              hipStream_t stream) {
  (void)in_sizes; (void)n_in; (void)out_size; (void)ws_size;
  const float* hidden = (const float*)d_in[0];
  const float* cosT = (const float*)d_in[1];
  const float* sinT = (const float*)d_in[2];
  // d_in[3] = attention_mask: exactly causal triu * -1e9 -> computed analytically
  const float* Wq = (const float*)d_in[4];
  const float* Wk = (const float*)d_in[5];
  const float* Wv = (const float*)d_in[6];
  const float* Wo = (const float*)d_in[7];
  const float* qnw = (const float*)d_in[8];
  const float* knw = (const float*)d_in[9];
  float* out = (float*)d_out;

  char* ws = (char*)d_ws;
  size_t off = 0;
  auto alloc = [&](size_t bytes) {
    char* p = ws + off;
    off += (bytes + 255) & ~(size_t)255;
    return p;
  };
  f16* hb = (f16*)alloc(4096ull * 1024 * 2);
  f16* wqkv = (f16*)alloc(4096ull * 1024 * 2);   // [Wq;Wk;Wv] rows
  f16* wob = (f16*)alloc(1024ull * 2048 * 2);
  float* qkvf = (float*)alloc(4096ull * 4096 * 4);
  f16* qt = (f16*)alloc(32ull * 2048 * 128 * 2);
  f16* kt = (f16*)alloc(16ull * 2048 * 128 * 2);
  f16* vt = (f16*)alloc(16ull * 2048 * 128 * 2);
  f16* ot = (f16*)alloc(4096ull * 2048 * 2);

  cast_f32_f16<<<4096, 256, 0, stream>>>(hidden, hb, 4194304);
  cast_f32_f16<<<2048, 256, 0, stream>>>(Wq, wqkv, 2097152);
  cast_f32_f16<<<1024, 256, 0, stream>>>(Wk, wqkv + 2048ull * 1024, 1048576);
  cast_f32_f16<<<1024, 256, 0, stream>>>(Wv, wqkv + 3072ull * 1024, 1048576);
  cast_f32_f16<<<2048, 256, 0, stream>>>(Wo, wob, 2097152);

  gemm_bt<<<dim3(32, 32), 256, 0, stream>>>(hb, wqkv, qkvf, 4096, 4096, 1024);

  rope_norm<<<24576, 256, 0, stream>>>(qkvf, cosT, sinT, qnw, knw, qt, kt);
  v_transpose<<<dim3(32, 16), 256, 0, stream>>>(qkvf, vt);

  attn<<<1024, 128, 0, stream>>>(qt, kt, vt, ot);

  gemm_bt<<<dim3(8, 32), 256, 0, stream>>>(ot, wob, out, 4096, 1024, 2048);
}